// Round 2
// baseline (766.944 us; speedup 1.0000x reference)
//
#include <hip/hip_runtime.h>
#include <hip/hip_fp16.h>

typedef _Float16 f16;
typedef f16 f16x8 __attribute__((ext_vector_type(8)));
typedef f16 f16x4 __attribute__((ext_vector_type(4)));
typedef float f32x4 __attribute__((ext_vector_type(4)));

#define D_DIM 256
#define L_DIM 200
#define LROWS_MAX 112   // rows held in LDS per block (half 0: 112, half 1: 96 used)
#define HSTR 260        // fp16 row stride with +4 pad (measured: 0 bank conflicts)

__device__ __forceinline__ f16x8 cvt8(f32x4 x0, f32x4 x1) {
    f16x8 a;
    a[0] = (f16)x0[0]; a[1] = (f16)x0[1]; a[2] = (f16)x0[2]; a[3] = (f16)x0[3];
    a[4] = (f16)x1[0]; a[5] = (f16)x1[1]; a[6] = (f16)x1[2]; a[7] = (f16)x1[3];
    return a;
}

// One block = one (batch, branch, L-half). Emits flash-style partial:
// pw[0..255] = sum_l e^{s_l - m} * H[l][:], pw[256] = m, pw[257] = z = sum_l e^{s_l - m}
__global__ __launch_bounds__(512, 4)
void fused_half(const float* __restrict__ M, const float* __restrict__ N,
                const float* __restrict__ act_r,
                const float* __restrict__ Wm, const float* __restrict__ bm,
                const float* __restrict__ Wn, const float* __restrict__ bn,
                float* __restrict__ pws) {
    const int b    = blockIdx.x;
    const int br   = blockIdx.y;
    const int half = blockIdx.z;
    const int NT    = half ? 6  : 7;    // 16-row tiles
    const int LROWS = half ? 96 : 112;  // tile-padded rows
    const int VR    = half ? 88 : 112;  // valid rows (global 112..199 for half 1)
    const int row0  = half ? 112 : 0;

    const float* __restrict__ X    = (br ? N : M) + (size_t)b * (L_DIM * D_DIM);
    const float* __restrict__ W    = br ? Wn : Wm;
    const float* __restrict__ bias = br ? bn : bm;

    __shared__ f16   Hs[LROWS_MAX * HSTR];   // 58240 B
    __shared__ float scores[LROWS_MAX];
    __shared__ float att[LROWS_MAX];
    __shared__ float part[8][D_DIM];
    __shared__ float red[16];

    const int tid  = threadIdx.x;
    const int lane = tid & 63;
    const int wv   = tid >> 6;          // wave owns cols [wv*32, wv*32+32)
    const int r16  = lane & 15;
    const int g    = lane >> 4;

    if (tid < LROWS_MAX) scores[tid] = 0.f;

    // ---- B fragments straight from fp32 W (L2-resident), bias, act_r ----
    f16x8 Bf[2][8];
    float arv[2], bv[2];
    #pragma unroll
    for (int nt = 0; nt < 2; ++nt) {
        const int col = wv * 32 + nt * 16 + r16;
        arv[nt] = act_r[b * D_DIM + col];
        bv[nt]  = bias[col];
        #pragma unroll
        for (int ks = 0; ks < 8; ++ks) {
            f32x4 w0 = *(const f32x4*)(W + col * D_DIM + ks * 32 + g * 8);
            f32x4 w1 = *(const f32x4*)(W + col * D_DIM + ks * 32 + g * 8 + 4);
            Bf[nt][ks] = cvt8(w0, w1);
        }
    }
    __syncthreads();   // scores init visible before atomics

    // ---- prologue: prefetch tile 0, ks 0..3 (8 x f32x4 = 32 VGPR) ----
    f32x4 R[8];
    const float* xr = X + (size_t)min(row0 + r16, L_DIM - 1) * D_DIM;
    #pragma unroll
    for (int k = 0; k < 4; ++k) {
        R[2*k]   = *(const f32x4*)(xr + k * 32 + g * 8);
        R[2*k+1] = *(const f32x4*)(xr + k * 32 + g * 8 + 4);
    }

    // ---- main loop: GEMM + bias + ReLU + score partials ----
    for (int mt = 0; mt < NT; ++mt) {
        f32x4 acc0 = {0.f, 0.f, 0.f, 0.f}, acc1 = {0.f, 0.f, 0.f, 0.f};
        #pragma unroll
        for (int ks = 0; ks < 4; ++ks) {
            f16x8 a = cvt8(R[2*ks], R[2*ks+1]);
            acc0 = __builtin_amdgcn_mfma_f32_16x16x32_f16(a, Bf[0][ks], acc0, 0, 0, 0);
            acc1 = __builtin_amdgcn_mfma_f32_16x16x32_f16(a, Bf[1][ks], acc1, 0, 0, 0);
        }
        const float* xr_cur = xr;
        if (mt + 1 < NT) {   // prefetch next tile's ks 0..3; in flight across MFMA+epilogue
            const float* xn = X + (size_t)min(row0 + (mt + 1) * 16 + r16, L_DIM - 1) * D_DIM;
            #pragma unroll
            for (int k = 0; k < 4; ++k) {
                R[2*k]   = *(const f32x4*)(xn + k * 32 + g * 8);
                R[2*k+1] = *(const f32x4*)(xn + k * 32 + g * 8 + 4);
            }
            xr = xn;
        }
        #pragma unroll
        for (int ks = 4; ks < 8; ++ks) {
            f32x4 q0 = *(const f32x4*)(xr_cur + ks * 32 + g * 8);
            f32x4 q1 = *(const f32x4*)(xr_cur + ks * 32 + g * 8 + 4);
            f16x8 a = cvt8(q0, q1);
            acc0 = __builtin_amdgcn_mfma_f32_16x16x32_f16(a, Bf[0][ks], acc0, 0, 0, 0);
            acc1 = __builtin_amdgcn_mfma_f32_16x16x32_f16(a, Bf[1][ks], acc1, 0, 0, 0);
        }
        // epilogue: bias + ReLU + Hs store + score partials
        float sc[4];
        const int colc = wv * 32 + r16;
        #pragma unroll
        for (int r = 0; r < 4; ++r) {
            const int rr = mt * 16 + g * 4 + r;   // local row
            float h0 = acc0[r] + bv[0]; h0 = h0 > 0.f ? h0 : 0.f;
            float h1 = acc1[r] + bv[1]; h1 = h1 > 0.f ? h1 : 0.f;
            Hs[rr * HSTR + colc]      = (f16)h0;
            Hs[rr * HSTR + colc + 16] = (f16)h1;
            sc[r] = (rr < VR) ? (h0 * arv[0] + h1 * arv[1]) : 0.f;
        }
        #pragma unroll
        for (int r = 0; r < 4; ++r) {
            float v = sc[r];
            v += __shfl_xor(v, 1);
            v += __shfl_xor(v, 2);
            v += __shfl_xor(v, 4);
            v += __shfl_xor(v, 8);
            const int rr = mt * 16 + g * 4 + r;
            if (r16 == 0 && rr < VR) atomicAdd(&scores[rr], v);
        }
    }
    __syncthreads();

    // ---- partial softmax over this block's rows ----
    const float s = (tid < VR) ? scores[tid] : -3.0e38f;
    float mx = s;
    #pragma unroll
    for (int sh = 32; sh >= 1; sh >>= 1) mx = fmaxf(mx, __shfl_xor(mx, sh));
    if (lane == 0) red[wv] = mx;
    __syncthreads();
    if (tid == 0) {
        float mm = red[0];
        #pragma unroll
        for (int i = 1; i < 8; ++i) mm = fmaxf(mm, red[i]);
        red[8] = mm;
    }
    __syncthreads();
    const float bmax = red[8];
    const float e = (tid < VR) ? __expf(s - bmax) : 0.f;
    if (tid < LROWS_MAX) att[tid] = e;      // rows >= VR get 0
    float z = e;
    #pragma unroll
    for (int sh = 32; sh >= 1; sh >>= 1) z += __shfl_xor(z, sh);
    __syncthreads();                        // red[8] consumed by all
    if (lane == 0) red[wv] = z;
    __syncthreads();
    if (tid == 0) {
        float zz = 0.f;
        #pragma unroll
        for (int i = 0; i < 8; ++i) zz += red[i];
        red[9] = zz;
    }
    __syncthreads();   // att + red[9] ready

    // ---- pvec[col] = sum_l att[l] * H[l][col] ----
    {
        const int colq = (tid & 63) * 4;
        const int q    = tid >> 6;
        const int rpq  = LROWS >> 3;        // 14 or 12
        float a0 = 0.f, a1 = 0.f, a2 = 0.f, a3 = 0.f;
        const int l0 = q * rpq;
        for (int l = l0; l < l0 + rpq; ++l) {
            const float al = att[l];
            f16x4 hv = *(const f16x4*)(&Hs[l * HSTR + colq]);
            a0 += al * (float)hv[0];
            a1 += al * (float)hv[1];
            a2 += al * (float)hv[2];
            a3 += al * (float)hv[3];
        }
        part[q][colq + 0] = a0;
        part[q][colq + 1] = a1;
        part[q][colq + 2] = a2;
        part[q][colq + 3] = a3;
    }
    __syncthreads();
    float* __restrict__ pw = pws + (((size_t)b * 2 + br) * 2 + half) * 258;
    if (tid < D_DIM) {
        float sum = 0.f;
        #pragma unroll
        for (int qq = 0; qq < 8; ++qq) sum += part[qq][tid];
        pw[tid] = sum;
    }
    if (tid == 256) pw[256] = red[8];
    if (tid == 257) pw[257] = red[9];
}

// Merge the two L-halves' flash partials: out = (e0*v0 + e1*v1) / ((e0*z0 + e1*z1) * L)
__global__ void combine_halves(const float* __restrict__ pws, float* __restrict__ out) {
    const int pair = blockIdx.x;            // b*2 + br
    const int col  = threadIdx.x;           // 0..255
    const float* p0 = pws + (size_t)(pair * 2 + 0) * 258;
    const float* p1 = pws + (size_t)(pair * 2 + 1) * 258;
    const float m0 = p0[256], z0 = p0[257];
    const float m1 = p1[256], z1 = p1[257];
    const float m  = fmaxf(m0, m1);
    const float e0 = __expf(m0 - m), e1 = __expf(m1 - m);
    const float zi = 1.f / ((z0 * e0 + z1 * e1) * (float)L_DIM);
    const float v  = p0[col] * e0 + p1[col] * e1;
    const int bb = pair >> 1, rb = pair & 1;
    out[(size_t)bb * (2 * D_DIM) + rb * D_DIM + col] = v * zi;
}

extern "C" void kernel_launch(void* const* d_in, const int* in_sizes, int n_in,
                              void* d_out, int out_size, void* d_ws, size_t ws_size,
                              hipStream_t stream) {
    const float* M     = (const float*)d_in[0];
    const float* N     = (const float*)d_in[1];
    const float* act_r = (const float*)d_in[2];
    const float* Wm    = (const float*)d_in[3];
    const float* bm    = (const float*)d_in[4];
    const float* Wn    = (const float*)d_in[5];
    const float* bn    = (const float*)d_in[6];
    float* out = (float*)d_out;
    float* pws = (float*)d_ws;   // B*2*2*258 floats = 4.23 MB

    const int B = in_sizes[2] / D_DIM;   // 1024

    dim3 grid(B, 2, 2);
    fused_half<<<grid, 512, 0, stream>>>(M, N, act_r, Wm, bm, Wn, bn, pws);
    combine_halves<<<B * 2, D_DIM, 0, stream>>>(pws, out);
}